// Round 4
// baseline (307.975 us; speedup 1.0000x reference)
//
#include <hip/hip_runtime.h>
#include <math.h>

#define B 64
#define D 256
#define M 8000
#define N 32
#define LG_LD 8000
#define EPB 8

typedef unsigned short u16;
typedef __bf16 bf16x8 __attribute__((ext_vector_type(8)));
typedef float fx4 __attribute__((ext_vector_type(4)));

#define STR_E  264   // u16 stride of sE rows (n-major): 528B, 16B-aligned, bank-optimal
#define STR_P  40    // u16 stride of sP rows (b-major)
// sET: interleaved layout. u16 index of (d, slot) = (d>>2)*136 + (slot>>3)*32 + (d&3)*8 + (slot&7)
// slot = sigma(n) = 4*(n&7) + (n>>3)  (global k-permutation, applied to BOTH P and E^T)

static __device__ __forceinline__ u16 f2bf(float x) {
    unsigned int u = __float_as_uint(x);
    u += 0x7FFFu + ((u >> 16) & 1u);
    return (u16)(u >> 16);
}

// ---------------- wordemb fp32 -> bf16 (+ query -> bf16) ----------------
__global__ __launch_bounds__(256) void k_conv(const float* __restrict__ emb,
                                              u16* __restrict__ embb,
                                              const float* __restrict__ query,
                                              u16* __restrict__ qbf) {
    int t = threadIdx.x;
    if (blockIdx.x < 6250) {
        size_t idx = (size_t)blockIdx.x * 2048 + (size_t)t * 8;
        float4 v0 = *(const float4*)(emb + idx);
        float4 v1 = *(const float4*)(emb + idx + 4);
        u16 h[8] = {f2bf(v0.x), f2bf(v0.y), f2bf(v0.z), f2bf(v0.w),
                    f2bf(v1.x), f2bf(v1.y), f2bf(v1.z), f2bf(v1.w)};
        *(uint4*)(embb + idx) = *(uint4*)h;
    } else {
        size_t idx = (size_t)(blockIdx.x - 6250) * 2048 + (size_t)t * 8;
        float4 v0 = *(const float4*)(query + idx);
        float4 v1 = *(const float4*)(query + idx + 4);
        u16 h[8] = {f2bf(v0.x), f2bf(v0.y), f2bf(v0.z), f2bf(v0.w),
                    f2bf(v1.x), f2bf(v1.y), f2bf(v1.z), f2bf(v1.w)};
        *(uint4*)(qbf + idx) = *(uint4*)h;
    }
}

// ---------------- fused: gather keys_e (bf16, blocks 0..999) + vq proj (1000..1063) ----------------
__global__ __launch_bounds__(256) void k_pre(const int* __restrict__ keys,
                                             const u16* __restrict__ embb,
                                             const float* __restrict__ q,
                                             const float* __restrict__ W,
                                             const float* __restrict__ bias,
                                             u16* __restrict__ keb,
                                             u16* __restrict__ vqb) {
    __shared__ float qs[D];
    int t = threadIdx.x;
    if (blockIdx.x < 1000) {
        int c = blockIdx.x * 256 + t;       // over 8000*32 16B-chunks
        int j = c >> 5, sp = c & 31;
        int id = keys[j];
        uint4 v = *(const uint4*)(embb + (size_t)id * D + sp * 8);
        if (id == 0) v = make_uint4(0u, 0u, 0u, 0u);
        *(uint4*)(keb + (size_t)j * D + sp * 8) = v;
    } else {
        int b = blockIdx.x - 1000;
        qs[t] = q[b * D + t];
        __syncthreads();
        const float* wr = W + t * D;
        float acc = bias[t];
#pragma unroll 8
        for (int k = 0; k < D; k += 4) {
            float4 w4 = *(const float4*)(wr + k);
            acc += qs[k] * w4.x + qs[k + 1] * w4.y + qs[k + 2] * w4.z + qs[k + 3] * w4.w;
        }
        vqb[b * D + t] = f2bf(acc);
    }
}

// ---------------- logits_e = q @ keys_e^T via bf16 MFMA, no LDS ----------------
// 500 blocks x 16-m tile; wave w covers b-tile 16w. Frags straight from global.
__global__ __launch_bounds__(256) void k_logits(const u16* __restrict__ qbf,
                                                const u16* __restrict__ keb,
                                                float* __restrict__ lg) {
    int t = threadIdx.x;
    int lane = t & 63, l = lane & 15, q = lane >> 4, w = t >> 6;
    int m0 = blockIdx.x * 16;
    int b0 = 16 * w;
    fx4 acc = {0.f, 0.f, 0.f, 0.f};
#pragma unroll
    for (int s = 0; s < 8; ++s) {
        bf16x8 a  = *(const bf16x8*)(qbf + (size_t)(b0 + l) * D + 32 * s + 8 * q);
        bf16x8 bb = *(const bf16x8*)(keb + (size_t)(m0 + l) * D + 32 * s + 8 * q);
        acc = __builtin_amdgcn_mfma_f32_16x16x32_bf16(a, bb, acc, 0, 0, 0);
    }
#pragma unroll
    for (int r = 0; r < 4; ++r)
        lg[(size_t)(b0 + 4 * q + r) * LG_LD + m0 + l] = acc[r];
}

// ---------------- per-b row max & 1/sum(exp) over m ----------------
__global__ __launch_bounds__(256) void k_stats(const float* __restrict__ lg,
                                               float* __restrict__ rmax,
                                               float* __restrict__ rsinv) {
    int b = blockIdx.x, t = threadIdx.x;
    __shared__ float red[256];
    const float* row = lg + b * LG_LD;
    float mx = -INFINITY;
    for (int j = t; j < M; j += 256) mx = fmaxf(mx, row[j]);
    red[t] = mx; __syncthreads();
    for (int s = 128; s > 0; s >>= 1) {
        if (t < s) red[t] = fmaxf(red[t], red[t + s]);
        __syncthreads();
    }
    mx = red[0]; __syncthreads();
    float sm = 0.f;
    for (int j = t; j < M; j += 256) sm += __expf(row[j] - mx);
    red[t] = sm; __syncthreads();
    for (int s = 128; s > 0; s >>= 1) {
        if (t < s) red[t] += red[t + s];
        __syncthreads();
    }
    if (t == 0) { rmax[b] = mx; rsinv[b] = 1.f / red[0]; }
}

// ---------------- wT[m][b] = prob_e[b][m]  (LDS transpose) ----------------
__global__ __launch_bounds__(256) void k_w(const float* __restrict__ lg,
                                           const float* __restrict__ rmax,
                                           const float* __restrict__ rsinv,
                                           float* __restrict__ wT) {
    __shared__ float tile[64][65];
    int t = threadIdx.x;
    int x = t & 63, y = t >> 6;
    int m0 = blockIdx.x * 64;
#pragma unroll
    for (int i = 0; i < 16; ++i) {
        int b = 4 * i + y;
        tile[b][x] = __expf(lg[b * LG_LD + m0 + x] - rmax[b]) * rsinv[b];
    }
    __syncthreads();
#pragma unroll
    for (int i = 0; i < 16; ++i) {
        int m = 4 * i + y;
        wT[(m0 + m) * 64 + x] = tile[x][m];
    }
}

// ---------------- o_k = prob_e @ keys_e (bf16 keys) ----------------
__global__ __launch_bounds__(256) void k_ok(const u16* __restrict__ keb,
                                            const float* __restrict__ wT,
                                            float* __restrict__ o_k) {
    int t = threadIdx.x;
    int bg = blockIdx.x >> 5;
    int jc = blockIdx.x & 31;
    int j0 = jc * 250;
    float acc[16] = {};
    for (int j = j0; j < j0 + 250; ++j) {
        float kv = __uint_as_float(((unsigned)keb[(size_t)j * D + t]) << 16);
        const float4* w4 = (const float4*)(wT + j * 64 + bg * 16);
        float4 wa = w4[0], wb = w4[1], wc = w4[2], wd = w4[3];
        acc[0]  += wa.x * kv; acc[1]  += wa.y * kv; acc[2]  += wa.z * kv; acc[3]  += wa.w * kv;
        acc[4]  += wb.x * kv; acc[5]  += wb.y * kv; acc[6]  += wb.z * kv; acc[7]  += wb.w * kv;
        acc[8]  += wc.x * kv; acc[9]  += wc.y * kv; acc[10] += wc.z * kv; acc[11] += wc.w * kv;
        acc[12] += wd.x * kv; acc[13] += wd.y * kv; acc[14] += wd.z * kv; acc[15] += wd.w * kv;
    }
#pragma unroll
    for (int i = 0; i < 16; ++i)
        atomicAdd(&o_k[(bg * 16 + i) * D + t], acc[i]);
}

// ---------------- heavy: per-entry value attention, bf16 MFMA, bf16 gather ----------------
__global__ __launch_bounds__(256, 4) void k_heavy(const int* __restrict__ entries,
                                                  const u16* __restrict__ embb,
                                                  const u16* __restrict__ vqb,
                                                  const float* __restrict__ wTp,
                                                  float* __restrict__ comb) {
    __shared__ __align__(16) u16 sEu[N * STR_E];     // 16,896 B  row-major E (n x d)
    __shared__ __align__(16) u16 sETu[64 * 136];     // 17,408 B  sigma-permuted E^T, interleaved
    __shared__ __align__(16) u16 sPu[B * STR_P];     //  5,120 B  P (b x slot)
    __shared__ float sw[B];

    int t = threadIdx.x;
    int lane = t & 63, l = lane & 15, q = lane >> 4, w = t >> 6;
    int b0 = 16 * w;
    int sp = t & 31, n0 = t >> 5;      // gather: 16B-chunk sp of rows n0+8i

    // persistent vq B-fragments
    bf16x8 vqf[8];
#pragma unroll
    for (int s = 0; s < 8; ++s)
        vqf[s] = *(const bf16x8*)(vqb + (b0 + l) * D + 32 * s + 8 * q);

    fx4 zero4 = {0.f, 0.f, 0.f, 0.f};
    fx4 acc[16];
#pragma unroll
    for (int dt = 0; dt < 16; ++dt) acc[dt] = zero4;

    int m0 = blockIdx.x * EPB;

    // pipeline prologue: ids(e0) -> rows(e0) -> ids(e1)
    int idc[4], idn[4];
#pragma unroll
    for (int i = 0; i < 4; ++i) idc[i] = entries[m0 * N + n0 + 8 * i];
    uint4 pf[4];
#pragma unroll
    for (int i = 0; i < 4; ++i)
        pf[i] = *(const uint4*)(embb + (size_t)idc[i] * D + sp * 8);
#pragma unroll
    for (int i = 0; i < 4; ++i) idn[i] = entries[(m0 + 1) * N + n0 + 8 * i];

    int offL = (l >> 2) * 136 + (l & 3) * 8;   // sET read base for this lane

    for (int e = 0; e < EPB; ++e) {
        __syncthreads();                   // prev entry's PV reads of LDS done
        // ---- stage entry e: mask in place, write sE (b128) + sET (b64, sigma slots) ----
#pragma unroll
        for (int i = 0; i < 4; ++i) {
            if (idc[i] == 0) pf[i] = make_uint4(0u, 0u, 0u, 0u);
            *(uint4*)&sEu[(n0 + 8 * i) * STR_E + sp * 8] = pf[i];
        }
#pragma unroll
        for (int j = 0; j < 8; ++j) {
            unsigned a0 = (((unsigned*)&pf[0])[j >> 1] >> ((j & 1) * 16)) & 0xFFFFu;
            unsigned a1 = (((unsigned*)&pf[1])[j >> 1] >> ((j & 1) * 16)) & 0xFFFFu;
            unsigned a2 = (((unsigned*)&pf[2])[j >> 1] >> ((j & 1) * 16)) & 0xFFFFu;
            unsigned a3 = (((unsigned*)&pf[3])[j >> 1] >> ((j & 1) * 16)) & 0xFFFFu;
            uint2 pr = make_uint2(a0 | (a1 << 16), a2 | (a3 << 16));
            int off = (2 * sp + (j >> 2)) * 136 + (n0 >> 1) * 32 + (j & 3) * 8 + (n0 & 1) * 4;
            *(uint2*)&sETu[off] = pr;
        }
        if (t < B) sw[t] = wTp[(m0 + e) * B + t];
        // ---- prefetch entry e+1 rows, then e+2 ids ----
        if (e + 1 < EPB) {
#pragma unroll
            for (int i = 0; i < 4; ++i)
                pf[i] = *(const uint4*)(embb + (size_t)idn[i] * D + sp * 8);
#pragma unroll
            for (int i = 0; i < 4; ++i) idc[i] = idn[i];
            if (e + 2 < EPB) {
#pragma unroll
                for (int i = 0; i < 4; ++i) idn[i] = entries[(m0 + e + 2) * N + n0 + 8 * i];
            }
        }
        __syncthreads();
        // ---- S^T = E . vq^T ----
        fx4 accS[2];
        accS[0] = zero4; accS[1] = zero4;
#pragma unroll
        for (int T = 0; T < 2; ++T)
#pragma unroll
            for (int s = 0; s < 8; ++s) {
                bf16x8 ea = *(const bf16x8*)&sEu[(16 * T + l) * STR_E + 32 * s + 8 * q];
                accS[T] = __builtin_amdgcn_mfma_f32_16x16x32_bf16(ea, vqf[s], accS[T], 0, 0, 0);
            }
        // ---- softmax over n (lane holds n = 16T+4q+r at b = b0+l), fold prob_e ----
        float swb = sw[b0 + l];
        float mx = -INFINITY;
#pragma unroll
        for (int T = 0; T < 2; ++T)
#pragma unroll
            for (int r = 0; r < 4; ++r) mx = fmaxf(mx, accS[T][r]);
        mx = fmaxf(mx, __shfl_xor(mx, 16));
        mx = fmaxf(mx, __shfl_xor(mx, 32));
        float pe[2][4], sum = 0.f;
#pragma unroll
        for (int T = 0; T < 2; ++T)
#pragma unroll
            for (int r = 0; r < 4; ++r) {
                pe[T][r] = __expf(accS[T][r] - mx);
                sum += pe[T][r];
            }
        sum += __shfl_xor(sum, 16);
        sum += __shfl_xor(sum, 32);
        float sc = swb / sum;
        // ---- write P at sigma-permuted slots (wave-private rows -> no barrier) ----
#pragma unroll
        for (int T = 0; T < 2; ++T)
#pragma unroll
            for (int r = 0; r < 4; ++r) {
                int nn = 16 * T + 4 * q + r;
                int slot = 4 * (nn & 7) + (nn >> 3);
                sPu[(b0 + l) * STR_P + slot] = f2bf(pe[T][r] * sc);
            }
        // ---- PV: combined += P . E ----
        bf16x8 pa = *(const bf16x8*)&sPu[(b0 + l) * STR_P + 8 * q];
#pragma unroll
        for (int dt = 0; dt < 16; ++dt) {
            bf16x8 eb = *(const bf16x8*)&sETu[offL + dt * 544 + q * 32];
            acc[dt] = __builtin_amdgcn_mfma_f32_16x16x32_bf16(pa, eb, acc[dt], 0, 0, 0);
        }
    }
    // ---- epilogue: lane (q,l) reg r holds combined[b0+4q+r][16dt+l] ----
#pragma unroll
    for (int dt = 0; dt < 16; ++dt)
#pragma unroll
        for (int r = 0; r < 4; ++r)
            atomicAdd(&comb[(b0 + 4 * q + r) * D + 16 * dt + l], acc[dt][r]);
}

extern "C" void kernel_launch(void* const* d_in, const int* in_sizes, int n_in,
                              void* d_out, int out_size, void* d_ws, size_t ws_size,
                              hipStream_t stream) {
    const int*   keys    = (const int*)d_in[0];
    const int*   entries = (const int*)d_in[1];
    const float* query   = (const float*)d_in[2];
    const float* wordemb = (const float*)d_in[3];
    const float* qproj_w = (const float*)d_in[4];
    const float* qproj_b = (const float*)d_in[5];

    float* out   = (float*)d_out;
    float* o_k   = out;
    float* lg    = out + B * D;
    float* comb  = out + B * D + B * M;

    char* wsb = (char*)d_ws;
    u16*   embb  = (u16*)wsb;                          // 25,600,000 B
    u16*   keb   = (u16*)(wsb + 25600000);             //  4,096,000 B
    u16*   qbf   = (u16*)(wsb + 29696000);             //     32,768 B
    u16*   vqb   = (u16*)(wsb + 29728768);             //     32,768 B
    float* wT    = (float*)(wsb + 29761536);           //  2,048,000 B
    float* rmax  = (float*)(wsb + 31809536);           //        256 B
    float* rsinv = (float*)(wsb + 31809792);           //        256 B

    hipMemsetAsync(o_k, 0, B * D * sizeof(float), stream);
    hipMemsetAsync(comb, 0, B * D * sizeof(float), stream);

    k_conv<<<6258, 256, 0, stream>>>(wordemb, embb, query, qbf);
    k_pre<<<1064, 256, 0, stream>>>(keys, embb, query, qproj_w, qproj_b, keb, vqb);
    k_logits<<<M / 16, 256, 0, stream>>>(qbf, keb, lg);
    k_stats<<<B, 256, 0, stream>>>(lg, rmax, rsinv);
    k_w<<<M / 64, 256, 0, stream>>>(lg, rmax, rsinv, wT);
    k_ok<<<128, 256, 0, stream>>>(keb, wT, o_k);
    k_heavy<<<M / EPB, 256, 0, stream>>>(entries, embb, vqb, wT, comb);
}

// Round 5
// 272.454 us; speedup vs baseline: 1.1304x; 1.1304x over previous
//
#include <hip/hip_runtime.h>
#include <math.h>

#define B 64
#define D 256
#define M 8000
#define N 32
#define LG_LD 8000
#define EPB 8

typedef unsigned short u16;
typedef __bf16 bf16x8 __attribute__((ext_vector_type(8)));
typedef float fx4 __attribute__((ext_vector_type(4)));

#define STR_E  264   // u16 stride of sE rows (n-major): 528B, 16B-aligned, bank-optimal
#define STR_P  40    // u16 stride of sP rows (b-major)
// sET: interleaved layout. u16 index of (d, slot) = (d>>2)*136 + (slot>>3)*32 + (d&3)*8 + (slot&7)
// slot = sigma(n) = 4*(n&7) + (n>>3)  (global k-permutation applied to BOTH P and E^T)

static __device__ __forceinline__ u16 f2bf(float x) {
    unsigned int u = __float_as_uint(x);
    u += 0x7FFFu + ((u >> 16) & 1u);
    return (u16)(u >> 16);
}
// monotone float<->uint key for atomicMax on floats
static __device__ __forceinline__ unsigned fmax_key(float f) {
    unsigned u = __float_as_uint(f);
    return (u & 0x80000000u) ? ~u : (u | 0x80000000u);
}
static __device__ __forceinline__ float fmax_unkey(unsigned t) {
    return __uint_as_float((t & 0x80000000u) ? (t & 0x7FFFFFFFu) : ~t);
}

// ---------------- zero: o_k, comb, rmax_u, ssum ----------------
__global__ __launch_bounds__(256) void k_zero(float* __restrict__ o_k,
                                              float* __restrict__ comb,
                                              unsigned* __restrict__ rmax_u,
                                              float* __restrict__ ssum) {
    int t = threadIdx.x;
    float4 z = make_float4(0.f, 0.f, 0.f, 0.f);
    if (blockIdx.x < 16) {
        ((float4*)o_k)[blockIdx.x * 256 + t] = z;
    } else if (blockIdx.x < 32) {
        ((float4*)comb)[(blockIdx.x - 16) * 256 + t] = z;
    } else {
        if (t < 64) rmax_u[t] = 0u;          // fmax_key of any real value is > 0
        else if (t < 128) ssum[t - 64] = 0.f;
    }
}

// ---------------- wordemb fp32 -> bf16 (+ query -> bf16) ----------------
__global__ __launch_bounds__(256) void k_conv(const float* __restrict__ emb,
                                              u16* __restrict__ embb,
                                              const float* __restrict__ query,
                                              u16* __restrict__ qbf) {
    int t = threadIdx.x;
    if (blockIdx.x < 6250) {
        size_t idx = (size_t)blockIdx.x * 2048 + (size_t)t * 8;
        float4 v0 = *(const float4*)(emb + idx);
        float4 v1 = *(const float4*)(emb + idx + 4);
        u16 h[8] = {f2bf(v0.x), f2bf(v0.y), f2bf(v0.z), f2bf(v0.w),
                    f2bf(v1.x), f2bf(v1.y), f2bf(v1.z), f2bf(v1.w)};
        *(uint4*)(embb + idx) = *(uint4*)h;
    } else {
        size_t idx = (size_t)(blockIdx.x - 6250) * 2048 + (size_t)t * 8;
        float4 v0 = *(const float4*)(query + idx);
        float4 v1 = *(const float4*)(query + idx + 4);
        u16 h[8] = {f2bf(v0.x), f2bf(v0.y), f2bf(v0.z), f2bf(v0.w),
                    f2bf(v1.x), f2bf(v1.y), f2bf(v1.z), f2bf(v1.w)};
        *(uint4*)(qbf + idx) = *(uint4*)h;
    }
}

// ---------------- fused: gather keys_e bf16 from fp32 emb (0..999) + vq proj (1000..1063) ----------------
__global__ __launch_bounds__(256) void k_pre(const int* __restrict__ keys,
                                             const float* __restrict__ emb,
                                             const float* __restrict__ q,
                                             const float* __restrict__ W,
                                             const float* __restrict__ bias,
                                             u16* __restrict__ keb,
                                             u16* __restrict__ vqb) {
    __shared__ float qs[D];
    int t = threadIdx.x;
    if (blockIdx.x < 1000) {
        int c = blockIdx.x * 256 + t;       // over 8000*32 chunks of 8 elems
        int j = c >> 5, sp = c & 31;
        int id = keys[j];
        const float* rp = emb + (size_t)id * D + sp * 8;
        float4 v0 = *(const float4*)rp;
        float4 v1 = *(const float4*)(rp + 4);
        float msk = (id != 0) ? 1.f : 0.f;
        u16 h[8] = {f2bf(v0.x * msk), f2bf(v0.y * msk), f2bf(v0.z * msk), f2bf(v0.w * msk),
                    f2bf(v1.x * msk), f2bf(v1.y * msk), f2bf(v1.z * msk), f2bf(v1.w * msk)};
        *(uint4*)(keb + (size_t)j * D + sp * 8) = *(uint4*)h;
    } else {
        int b = blockIdx.x - 1000;
        qs[t] = q[b * D + t];
        __syncthreads();
        const float* wr = W + t * D;
        float acc = bias[t];
#pragma unroll 8
        for (int k = 0; k < D; k += 4) {
            float4 w4 = *(const float4*)(wr + k);
            acc += qs[k] * w4.x + qs[k + 1] * w4.y + qs[k + 2] * w4.z + qs[k + 3] * w4.w;
        }
        vqb[b * D + t] = f2bf(acc);
    }
}

// ---------------- logits_e = q @ keys_e^T via bf16 MFMA (no LDS) + per-b atomicMax ----------------
__global__ __launch_bounds__(256) void k_logits(const u16* __restrict__ qbf,
                                                const u16* __restrict__ keb,
                                                float* __restrict__ lg,
                                                unsigned* __restrict__ rmax_u) {
    int t = threadIdx.x;
    int lane = t & 63, l = lane & 15, q = lane >> 4, w = t >> 6;
    int m0 = blockIdx.x * 16;
    int b0 = 16 * w;
    fx4 acc = {0.f, 0.f, 0.f, 0.f};
#pragma unroll
    for (int s = 0; s < 8; ++s) {
        bf16x8 a  = *(const bf16x8*)(qbf + (size_t)(b0 + l) * D + 32 * s + 8 * q);
        bf16x8 bb = *(const bf16x8*)(keb + (size_t)(m0 + l) * D + 32 * s + 8 * q);
        acc = __builtin_amdgcn_mfma_f32_16x16x32_bf16(a, bb, acc, 0, 0, 0);
    }
#pragma unroll
    for (int r = 0; r < 4; ++r) {
        lg[(size_t)(b0 + 4 * q + r) * LG_LD + m0 + l] = acc[r];
        float mx = acc[r];
        mx = fmaxf(mx, __shfl_xor(mx, 1));
        mx = fmaxf(mx, __shfl_xor(mx, 2));
        mx = fmaxf(mx, __shfl_xor(mx, 4));
        mx = fmaxf(mx, __shfl_xor(mx, 8));
        if (l == 0) atomicMax(&rmax_u[b0 + 4 * q + r], fmax_key(mx));
    }
}

// ---------------- wT'[m][b] = exp(lg[b][m]-rmax[b]) (unnormalized) + per-b sum ----------------
__global__ __launch_bounds__(256) void k_w(const float* __restrict__ lg,
                                           const unsigned* __restrict__ rmax_u,
                                           float* __restrict__ wT,
                                           float* __restrict__ ssum) {
    __shared__ float tile[64][65];
    __shared__ float psum[4][64];
    int t = threadIdx.x;
    int x = t & 63, y = t >> 6;
    int m0 = blockIdx.x * 64;
#pragma unroll
    for (int i = 0; i < 16; ++i) {
        int b = 4 * i + y;
        float rm = fmax_unkey(rmax_u[b]);
        tile[b][x] = __expf(lg[(size_t)b * LG_LD + m0 + x] - rm);
    }
    __syncthreads();
    float ps = 0.f;
#pragma unroll
    for (int i = 0; i < 16; ++i) {
        int m = 4 * i + y;
        float v = tile[x][m];
        wT[(m0 + m) * 64 + x] = v;
        ps += v;
    }
    psum[y][x] = ps;
    __syncthreads();
    if (t < 64)
        atomicAdd(&ssum[t], psum[0][t] + psum[1][t] + psum[2][t] + psum[3][t]);
}

// ---------------- o_k = (wT'^T @ keys_e) * rsinv ----------------
__global__ __launch_bounds__(256) void k_ok(const u16* __restrict__ keb,
                                            const float* __restrict__ wT,
                                            const float* __restrict__ ssum,
                                            float* __restrict__ o_k) {
    __shared__ float sinv[16];
    int t = threadIdx.x;
    int bg = blockIdx.x >> 5;
    int jc = blockIdx.x & 31;
    if (t < 16) sinv[t] = 1.f / ssum[bg * 16 + t];
    __syncthreads();
    int j0 = jc * 250;
    float acc[16] = {};
    for (int j = j0; j < j0 + 250; ++j) {
        float kv = __uint_as_float(((unsigned)keb[(size_t)j * D + t]) << 16);
        const float4* w4 = (const float4*)(wT + j * 64 + bg * 16);
        float4 wa = w4[0], wb = w4[1], wc = w4[2], wd = w4[3];
        acc[0]  += wa.x * kv; acc[1]  += wa.y * kv; acc[2]  += wa.z * kv; acc[3]  += wa.w * kv;
        acc[4]  += wb.x * kv; acc[5]  += wb.y * kv; acc[6]  += wb.z * kv; acc[7]  += wb.w * kv;
        acc[8]  += wc.x * kv; acc[9]  += wc.y * kv; acc[10] += wc.z * kv; acc[11] += wc.w * kv;
        acc[12] += wd.x * kv; acc[13] += wd.y * kv; acc[14] += wd.z * kv; acc[15] += wd.w * kv;
    }
#pragma unroll
    for (int i = 0; i < 16; ++i)
        atomicAdd(&o_k[(bg * 16 + i) * D + t], acc[i] * sinv[i]);
}

// ---------------- heavy: per-entry value attention, bf16 MFMA, bf16 gather ----------------
__global__ __launch_bounds__(256, 3) void k_heavy(const int* __restrict__ entries,
                                                  const u16* __restrict__ embb,
                                                  const u16* __restrict__ vqb,
                                                  const float* __restrict__ wTp,
                                                  const float* __restrict__ ssum,
                                                  float* __restrict__ comb) {
    __shared__ __align__(16) u16 sEu[N * STR_E];     // 16,896 B  row-major E (n x d)
    __shared__ __align__(16) u16 sETu[64 * 136];     // 17,408 B  sigma-permuted E^T, interleaved
    __shared__ __align__(16) u16 sPu[B * STR_P];     //  5,120 B  P (b x slot)
    __shared__ float sw[B];

    int t = threadIdx.x;
    int lane = t & 63, l = lane & 15, q = lane >> 4, w = t >> 6;
    int b0 = 16 * w;
    int sp = t & 31, n0 = t >> 5;      // gather: 16B-chunk sp of rows n0+8i

    float my_sinv = (t < B) ? 1.f / ssum[t] : 0.f;

    // persistent vq B-fragments
    bf16x8 vqf[8];
#pragma unroll
    for (int s = 0; s < 8; ++s)
        vqf[s] = *(const bf16x8*)(vqb + (b0 + l) * D + 32 * s + 8 * q);

    fx4 zero4 = {0.f, 0.f, 0.f, 0.f};
    fx4 acc[16];
#pragma unroll
    for (int dt = 0; dt < 16; ++dt) acc[dt] = zero4;

    int m0 = blockIdx.x * EPB;

    // pipeline prologue: ids(e0) -> rows(e0) -> ids(e1)
    int idc[4], idn[4];
#pragma unroll
    for (int i = 0; i < 4; ++i) idc[i] = entries[m0 * N + n0 + 8 * i];
    uint4 pf[4];
#pragma unroll
    for (int i = 0; i < 4; ++i)
        pf[i] = *(const uint4*)(embb + (size_t)idc[i] * D + sp * 8);
#pragma unroll
    for (int i = 0; i < 4; ++i) idn[i] = entries[(m0 + 1) * N + n0 + 8 * i];

    int offL = (l >> 2) * 136 + (l & 3) * 8;   // sET read base for this lane

    for (int e = 0; e < EPB; ++e) {
        __syncthreads();                   // prev entry's PV reads of LDS done
        // ---- stage entry e: mask in place, write sE (b128) + sET (b64, sigma slots) ----
#pragma unroll
        for (int i = 0; i < 4; ++i) {
            if (idc[i] == 0) pf[i] = make_uint4(0u, 0u, 0u, 0u);
            *(uint4*)&sEu[(n0 + 8 * i) * STR_E + sp * 8] = pf[i];
        }
#pragma unroll
        for (int j = 0; j < 8; ++j) {
            unsigned a0 = (((unsigned*)&pf[0])[j >> 1] >> ((j & 1) * 16)) & 0xFFFFu;
            unsigned a1 = (((unsigned*)&pf[1])[j >> 1] >> ((j & 1) * 16)) & 0xFFFFu;
            unsigned a2 = (((unsigned*)&pf[2])[j >> 1] >> ((j & 1) * 16)) & 0xFFFFu;
            unsigned a3 = (((unsigned*)&pf[3])[j >> 1] >> ((j & 1) * 16)) & 0xFFFFu;
            uint2 pr = make_uint2(a0 | (a1 << 16), a2 | (a3 << 16));
            int off = (2 * sp + (j >> 2)) * 136 + (n0 >> 1) * 32 + (j & 3) * 8 + (n0 & 1) * 4;
            *(uint2*)&sETu[off] = pr;
        }
        if (t < B) sw[t] = wTp[(m0 + e) * B + t] * my_sinv;
        // ---- prefetch entry e+1 rows, then e+2 ids ----
        if (e + 1 < EPB) {
#pragma unroll
            for (int i = 0; i < 4; ++i)
                pf[i] = *(const uint4*)(embb + (size_t)idn[i] * D + sp * 8);
#pragma unroll
            for (int i = 0; i < 4; ++i) idc[i] = idn[i];
            if (e + 2 < EPB) {
#pragma unroll
                for (int i = 0; i < 4; ++i) idn[i] = entries[(m0 + e + 2) * N + n0 + 8 * i];
            }
        }
        __syncthreads();
        // ---- S^T = E . vq^T ----
        fx4 accS[2];
        accS[0] = zero4; accS[1] = zero4;
#pragma unroll
        for (int T = 0; T < 2; ++T)
#pragma unroll
            for (int s = 0; s < 8; ++s) {
                bf16x8 ea = *(const bf16x8*)&sEu[(16 * T + l) * STR_E + 32 * s + 8 * q];
                accS[T] = __builtin_amdgcn_mfma_f32_16x16x32_bf16(ea, vqf[s], accS[T], 0, 0, 0);
            }
        // ---- softmax over n (lane holds n = 16T+4q+r at b = b0+l), fold prob_e ----
        float swb = sw[b0 + l];
        float mx = -INFINITY;
#pragma unroll
        for (int T = 0; T < 2; ++T)
#pragma unroll
            for (int r = 0; r < 4; ++r) mx = fmaxf(mx, accS[T][r]);
        mx = fmaxf(mx, __shfl_xor(mx, 16));
        mx = fmaxf(mx, __shfl_xor(mx, 32));
        float pe[2][4], sum = 0.f;
#pragma unroll
        for (int T = 0; T < 2; ++T)
#pragma unroll
            for (int r = 0; r < 4; ++r) {
                pe[T][r] = __expf(accS[T][r] - mx);
                sum += pe[T][r];
            }
        sum += __shfl_xor(sum, 16);
        sum += __shfl_xor(sum, 32);
        float sc = swb / sum;
        // ---- write P at sigma-permuted slots (wave-private rows -> no barrier) ----
#pragma unroll
        for (int T = 0; T < 2; ++T)
#pragma unroll
            for (int r = 0; r < 4; ++r) {
                int nn = 16 * T + 4 * q + r;
                int slot = 4 * (nn & 7) + (nn >> 3);
                sPu[(b0 + l) * STR_P + slot] = f2bf(pe[T][r] * sc);
            }
        // ---- PV: combined += P . E ----
        bf16x8 pa = *(const bf16x8*)&sPu[(b0 + l) * STR_P + 8 * q];
#pragma unroll
        for (int dt = 0; dt < 16; ++dt) {
            bf16x8 eb = *(const bf16x8*)&sETu[offL + dt * 544 + q * 32];
            acc[dt] = __builtin_amdgcn_mfma_f32_16x16x32_bf16(pa, eb, acc[dt], 0, 0, 0);
        }
    }
    // ---- epilogue: lane (q,l) reg r holds combined[b0+4q+r][16dt+l] ----
#pragma unroll
    for (int dt = 0; dt < 16; ++dt)
#pragma unroll
        for (int r = 0; r < 4; ++r)
            atomicAdd(&comb[(b0 + 4 * q + r) * D + 16 * dt + l], acc[dt][r]);
}

extern "C" void kernel_launch(void* const* d_in, const int* in_sizes, int n_in,
                              void* d_out, int out_size, void* d_ws, size_t ws_size,
                              hipStream_t stream) {
    const int*   keys    = (const int*)d_in[0];
    const int*   entries = (const int*)d_in[1];
    const float* query   = (const float*)d_in[2];
    const float* wordemb = (const float*)d_in[3];
    const float* qproj_w = (const float*)d_in[4];
    const float* qproj_b = (const float*)d_in[5];

    float* out   = (float*)d_out;
    float* o_k   = out;
    float* lg    = out + B * D;
    float* comb  = out + B * D + B * M;

    char* wsb = (char*)d_ws;
    u16*      embb   = (u16*)wsb;                      // 25,600,000 B
    u16*      keb    = (u16*)(wsb + 25600000);         //  4,096,000 B
    u16*      qbf    = (u16*)(wsb + 29696000);         //     32,768 B
    u16*      vqb    = (u16*)(wsb + 29728768);         //     32,768 B
    float*    wT     = (float*)(wsb + 29761536);       //  2,048,000 B
    unsigned* rmax_u = (unsigned*)(wsb + 31809536);    //        256 B
    float*    ssum   = (float*)(wsb + 31809792);       //        256 B

    k_zero<<<33, 256, 0, stream>>>(o_k, comb, rmax_u, ssum);
    k_conv<<<6258, 256, 0, stream>>>(wordemb, embb, query, qbf);
    k_pre<<<1064, 256, 0, stream>>>(keys, wordemb, query, qproj_w, qproj_b, keb, vqb);
    k_logits<<<M / 16, 256, 0, stream>>>(qbf, keb, lg, rmax_u);
    k_w<<<M / 64, 256, 0, stream>>>(lg, rmax_u, wT, ssum);
    k_ok<<<128, 256, 0, stream>>>(keb, wT, ssum, o_k);
    k_heavy<<<M / EPB, 256, 0, stream>>>(entries, embb, vqb, wT, ssum, comb);
}

// Round 6
// 190.752 us; speedup vs baseline: 1.6145x; 1.4283x over previous
//
#include <hip/hip_runtime.h>
#include <math.h>

#define B 64
#define D 256
#define M 8000
#define N 32
#define LG_LD 8000
#define EPB 16          // entries per block (flash k_heavy)
#define NBLK (M / EPB)  // 500

typedef unsigned short u16;
typedef __bf16 bf16x8 __attribute__((ext_vector_type(8)));
typedef float fx4 __attribute__((ext_vector_type(4)));

#define STR_E  264   // u16 stride of sE rows (n-major)
#define STR_P  40    // u16 stride of sP rows (b-major)
// sET interleaved layout: u16 idx of (d, slot) = (d>>2)*136 + (slot>>3)*32 + (d&3)*8 + (slot&7)
// entry-phase slot = sigma(n) = 4*(n&7) + (n>>3); key-phase slot2(m) = 2*(m&7) + (m>>3)

static __device__ __forceinline__ u16 f2bf(float x) {
    unsigned int u = __float_as_uint(x);
    u += 0x7FFFu + ((u >> 16) & 1u);
    return (u16)(u >> 16);
}
static __device__ __forceinline__ float bf2f(u16 h) {
    return __uint_as_float(((unsigned)h) << 16);
}
static __device__ __forceinline__ unsigned fmax_key(float f) {
    unsigned u = __float_as_uint(f);
    return (u & 0x80000000u) ? ~u : (u | 0x80000000u);
}
static __device__ __forceinline__ float fmax_unkey(unsigned t) {
    return __uint_as_float((t & 0x80000000u) ? (t & 0x7FFFFFFFu) : ~t);
}

// ==================== FLASH PATH ====================

// ---- k_prep: embb conv (0..6249) + qbf conv (6250..6257) + keb gather (6258..7257) + vq (7258..7321)
__global__ __launch_bounds__(256) void k_prep(const int* __restrict__ keys,
                                              const float* __restrict__ emb,
                                              const float* __restrict__ q,
                                              const float* __restrict__ W,
                                              const float* __restrict__ bias,
                                              u16* __restrict__ embb,
                                              u16* __restrict__ qbf,
                                              u16* __restrict__ keb,
                                              u16* __restrict__ vqb) {
    __shared__ float qs[D];
    int t = threadIdx.x, bid = blockIdx.x;
    if (bid < 6250) {
        size_t idx = (size_t)bid * 2048 + (size_t)t * 8;
        float4 v0 = *(const float4*)(emb + idx);
        float4 v1 = *(const float4*)(emb + idx + 4);
        u16 h[8] = {f2bf(v0.x), f2bf(v0.y), f2bf(v0.z), f2bf(v0.w),
                    f2bf(v1.x), f2bf(v1.y), f2bf(v1.z), f2bf(v1.w)};
        *(uint4*)(embb + idx) = *(uint4*)h;
    } else if (bid < 6258) {
        size_t idx = (size_t)(bid - 6250) * 2048 + (size_t)t * 8;
        float4 v0 = *(const float4*)(q + idx);
        float4 v1 = *(const float4*)(q + idx + 4);
        u16 h[8] = {f2bf(v0.x), f2bf(v0.y), f2bf(v0.z), f2bf(v0.w),
                    f2bf(v1.x), f2bf(v1.y), f2bf(v1.z), f2bf(v1.w)};
        *(uint4*)(qbf + idx) = *(uint4*)h;
    } else if (bid < 7258) {
        int c = (bid - 6258) * 256 + t;   // 8000*32 chunks of 8 elems
        int j = c >> 5, sp = c & 31;
        int id = keys[j];
        const float* rp = emb + (size_t)id * D + sp * 8;
        float4 v0 = *(const float4*)rp;
        float4 v1 = *(const float4*)(rp + 4);
        float msk = (id != 0) ? 1.f : 0.f;
        u16 h[8] = {f2bf(v0.x * msk), f2bf(v0.y * msk), f2bf(v0.z * msk), f2bf(v0.w * msk),
                    f2bf(v1.x * msk), f2bf(v1.y * msk), f2bf(v1.z * msk), f2bf(v1.w * msk)};
        *(uint4*)(keb + (size_t)j * D + sp * 8) = *(uint4*)h;
    } else {
        int b = bid - 7258;
        qs[t] = q[b * D + t];
        __syncthreads();
        const float* wr = W + t * D;
        float acc = bias[t];
#pragma unroll 8
        for (int k = 0; k < D; k += 4) {
            float4 w4 = *(const float4*)(wr + k);
            acc += qs[k] * w4.x + qs[k + 1] * w4.y + qs[k + 2] * w4.z + qs[k + 3] * w4.w;
        }
        vqb[b * D + t] = f2bf(acc);
    }
}

// ---- k_logits_f: logits via bf16 MFMA; writes lg (output) and lgT (ws, m-major)
__global__ __launch_bounds__(256) void k_logits_f(const u16* __restrict__ qbf,
                                                  const u16* __restrict__ keb,
                                                  float* __restrict__ lg,
                                                  float* __restrict__ lgT) {
    int t = threadIdx.x;
    int lane = t & 63, l = lane & 15, q = lane >> 4, w = t >> 6;
    int m0 = blockIdx.x * 16;
    int b0 = 16 * w;
    fx4 acc = {0.f, 0.f, 0.f, 0.f};
#pragma unroll
    for (int s = 0; s < 8; ++s) {
        bf16x8 a  = *(const bf16x8*)(qbf + (size_t)(b0 + l) * D + 32 * s + 8 * q);
        bf16x8 bb = *(const bf16x8*)(keb + (size_t)(m0 + l) * D + 32 * s + 8 * q);
        acc = __builtin_amdgcn_mfma_f32_16x16x32_bf16(a, bb, acc, 0, 0, 0);
    }
#pragma unroll
    for (int r = 0; r < 4; ++r) {
        lg[(size_t)(b0 + 4 * q + r) * LG_LD + m0 + l] = acc[r];
        lgT[(size_t)(m0 + l) * B + b0 + 4 * q + r] = acc[r];
    }
}

// ---- k_heavy_f: flash over entries; dbuf staging, 1 barrier/entry; partial numC/numK out
__global__ __launch_bounds__(256, 2) void k_heavy_f(const int* __restrict__ entries,
                                                    const u16* __restrict__ embb,
                                                    const u16* __restrict__ vqb,
                                                    const u16* __restrict__ keb,
                                                    const float* __restrict__ lgT,
                                                    u16* __restrict__ numCp,
                                                    u16* __restrict__ numKp,
                                                    float* __restrict__ mLp,
                                                    float* __restrict__ denLp) {
    __shared__ __align__(16) u16 sEu[2][N * STR_E];   // 33,792 B
    __shared__ __align__(16) u16 sETu[2][64 * 136];   // 34,816 B
    __shared__ __align__(16) u16 sPu[B * STR_P];      //  5,120 B
    __shared__ float sw[EPB][B];                      //  4,096 B
    __shared__ float red[4][B];                       //  1,024 B

    int t = threadIdx.x;
    int lane = t & 63, l = lane & 15, q = lane >> 4, w = t >> 6;
    int b0 = 16 * w;
    int sp = t & 31, n0 = t >> 5;
    int m0 = blockIdx.x * EPB;
    int bb = t & 63, y = t >> 6;

    // ---- flash prologue: local max / weights / denom over this block's 16 entries ----
    float lv[4];
#pragma unroll
    for (int i = 0; i < 4; ++i) lv[i] = lgT[(size_t)(m0 + 4 * i + y) * B + bb];
    float mx4 = fmaxf(fmaxf(lv[0], lv[1]), fmaxf(lv[2], lv[3]));
    red[y][bb] = mx4;
    __syncthreads();
    float mL = fmaxf(fmaxf(red[0][bb], red[1][bb]), fmaxf(red[2][bb], red[3][bb]));
    __syncthreads();
    float ds = 0.f;
#pragma unroll
    for (int i = 0; i < 4; ++i) {
        float wv = __expf(lv[i] - mL);
        sw[4 * i + y][bb] = wv;
        ds += wv;
    }
    red[y][bb] = ds;
    // persistent vq B-fragments
    bf16x8 vqf[8];
#pragma unroll
    for (int s = 0; s < 8; ++s)
        vqf[s] = *(const bf16x8*)(vqb + (b0 + l) * D + 32 * s + 8 * q);
    __syncthreads();
    if (t < B) {
        mLp[blockIdx.x * B + t] = mL;
        denLp[blockIdx.x * B + t] = red[0][t] + red[1][t] + red[2][t] + red[3][t];
    }

    fx4 zero4 = {0.f, 0.f, 0.f, 0.f};
    fx4 acc[16];
#pragma unroll
    for (int dt = 0; dt < 16; ++dt) acc[dt] = zero4;

    // ---- gather pipeline prologue: buf0 <- e0; pf <- e1; idn <- ids(e2) ----
    int idc[4], idn[4];
    uint4 pf[4];
#pragma unroll
    for (int i = 0; i < 4; ++i) idc[i] = entries[m0 * N + n0 + 8 * i];
#pragma unroll
    for (int i = 0; i < 4; ++i)
        pf[i] = *(const uint4*)(embb + (size_t)idc[i] * D + sp * 8);
#pragma unroll
    for (int i = 0; i < 4; ++i) {
        if (idc[i] == 0) pf[i] = make_uint4(0u, 0u, 0u, 0u);
        *(uint4*)&sEu[0][(n0 + 8 * i) * STR_E + sp * 8] = pf[i];
    }
#pragma unroll
    for (int j = 0; j < 8; ++j) {
        unsigned a0 = (((unsigned*)&pf[0])[j >> 1] >> ((j & 1) * 16)) & 0xFFFFu;
        unsigned a1 = (((unsigned*)&pf[1])[j >> 1] >> ((j & 1) * 16)) & 0xFFFFu;
        unsigned a2 = (((unsigned*)&pf[2])[j >> 1] >> ((j & 1) * 16)) & 0xFFFFu;
        unsigned a3 = (((unsigned*)&pf[3])[j >> 1] >> ((j & 1) * 16)) & 0xFFFFu;
        uint2 pr = make_uint2(a0 | (a1 << 16), a2 | (a3 << 16));
        int off = (2 * sp + (j >> 2)) * 136 + (n0 >> 1) * 32 + (j & 3) * 8 + (n0 & 1) * 4;
        *(uint2*)&sETu[0][off] = pr;
    }
#pragma unroll
    for (int i = 0; i < 4; ++i) idc[i] = entries[(m0 + 1) * N + n0 + 8 * i];
#pragma unroll
    for (int i = 0; i < 4; ++i)
        pf[i] = *(const uint4*)(embb + (size_t)idc[i] * D + sp * 8);
#pragma unroll
    for (int i = 0; i < 4; ++i) idn[i] = entries[(m0 + 2) * N + n0 + 8 * i];

    int offL = (l >> 2) * 136 + (l & 3) * 8;

    // ---- entry loop: 1 barrier per entry; compute e from buf[e&1] ----
#pragma unroll 2
    for (int e = 0; e < EPB; ++e) {
        __syncthreads();   // buf[e&1] staged; prev reads of buf[(e+1)&1] done; drains gather(e+1)
        int nxt = (e + 1) & 1;
        if (e < EPB - 1) {
            // (a) stage entry e+1 (held in pf) into buf[nxt]
#pragma unroll
            for (int i = 0; i < 4; ++i) {
                if (idc[i] == 0) pf[i] = make_uint4(0u, 0u, 0u, 0u);
                *(uint4*)&sEu[nxt][(n0 + 8 * i) * STR_E + sp * 8] = pf[i];
            }
#pragma unroll
            for (int j = 0; j < 8; ++j) {
                unsigned a0 = (((unsigned*)&pf[0])[j >> 1] >> ((j & 1) * 16)) & 0xFFFFu;
                unsigned a1 = (((unsigned*)&pf[1])[j >> 1] >> ((j & 1) * 16)) & 0xFFFFu;
                unsigned a2 = (((unsigned*)&pf[2])[j >> 1] >> ((j & 1) * 16)) & 0xFFFFu;
                unsigned a3 = (((unsigned*)&pf[3])[j >> 1] >> ((j & 1) * 16)) & 0xFFFFu;
                uint2 pr = make_uint2(a0 | (a1 << 16), a2 | (a3 << 16));
                int off = (2 * sp + (j >> 2)) * 136 + (n0 >> 1) * 32 + (j & 3) * 8 + (n0 & 1) * 4;
                *(uint2*)&sETu[nxt][off] = pr;
            }
            // (b) issue gather entry e+2 (stays in flight through this entry's compute)
            if (e < EPB - 2) {
#pragma unroll
                for (int i = 0; i < 4; ++i)
                    pf[i] = *(const uint4*)(embb + (size_t)idn[i] * D + sp * 8);
#pragma unroll
                for (int i = 0; i < 4; ++i) idc[i] = idn[i];
                if (e < EPB - 3) {
#pragma unroll
                    for (int i = 0; i < 4; ++i) idn[i] = entries[(m0 + e + 3) * N + n0 + 8 * i];
                }
            }
        }
        // (c) compute entry e from buf[cur]
        int cur = e & 1;
        fx4 accS[2];
        accS[0] = zero4; accS[1] = zero4;
#pragma unroll
        for (int T = 0; T < 2; ++T)
#pragma unroll
            for (int s = 0; s < 8; ++s) {
                bf16x8 ea = *(const bf16x8*)&sEu[cur][(16 * T + l) * STR_E + 32 * s + 8 * q];
                accS[T] = __builtin_amdgcn_mfma_f32_16x16x32_bf16(ea, vqf[s], accS[T], 0, 0, 0);
            }
        float swb = sw[e][b0 + l];
        float mx = -INFINITY;
#pragma unroll
        for (int T = 0; T < 2; ++T)
#pragma unroll
            for (int r = 0; r < 4; ++r) mx = fmaxf(mx, accS[T][r]);
        mx = fmaxf(mx, __shfl_xor(mx, 16));
        mx = fmaxf(mx, __shfl_xor(mx, 32));
        float pe[2][4], sum = 0.f;
#pragma unroll
        for (int T = 0; T < 2; ++T)
#pragma unroll
            for (int r = 0; r < 4; ++r) {
                pe[T][r] = __expf(accS[T][r] - mx);
                sum += pe[T][r];
            }
        sum += __shfl_xor(sum, 16);
        sum += __shfl_xor(sum, 32);
        float sc = swb / sum;
#pragma unroll
        for (int T = 0; T < 2; ++T)
#pragma unroll
            for (int r = 0; r < 4; ++r) {
                int nn = 16 * T + 4 * q + r;
                int slot = 4 * (nn & 7) + (nn >> 3);
                sPu[(b0 + l) * STR_P + slot] = f2bf(pe[T][r] * sc);
            }
        bf16x8 pa = *(const bf16x8*)&sPu[(b0 + l) * STR_P + 8 * q];
#pragma unroll
        for (int dt = 0; dt < 16; ++dt) {
            bf16x8 eb = *(const bf16x8*)&sETu[cur][offL + dt * 544 + q * 32];
            acc[dt] = __builtin_amdgcn_mfma_f32_16x16x32_bf16(pa, eb, acc[dt], 0, 0, 0);
        }
    }

    // ---- store numC partial (frees acc pressure; overlaps with numK staging) ----
    u16* ncp = numCp + (size_t)blockIdx.x * (B * D);
#pragma unroll
    for (int dt = 0; dt < 16; ++dt)
#pragma unroll
        for (int r = 0; r < 4; ++r)
            ncp[(b0 + 4 * q + r) * D + 16 * dt + l] = f2bf(acc[dt][r]);

    // ---- numK mini-PV: keys rows m0..m0+15, slot2(m) = 2*(m&7)+(m>>3); A zero-padded ----
    __syncthreads();   // all waves done reading sETu/sPu
    {
        int rp = t >> 5;   // 0..7
        uint4 ka = *(const uint4*)(keb + (size_t)(m0 + rp) * D + sp * 8);
        uint4 kb = *(const uint4*)(keb + (size_t)(m0 + rp + 8) * D + sp * 8);
#pragma unroll
        for (int j = 0; j < 8; ++j) {
            unsigned a0 = (((unsigned*)&ka)[j >> 1] >> ((j & 1) * 16)) & 0xFFFFu;
            unsigned a1 = (((unsigned*)&kb)[j >> 1] >> ((j & 1) * 16)) & 0xFFFFu;
            int d = 8 * sp + j;
            int sl = 2 * rp;   // slots 2rp, 2rp+1
            int off = (d >> 2) * 136 + (sl >> 3) * 32 + (d & 3) * 8 + (sl & 7);
            *(unsigned*)&sETu[0][off] = a0 | (a1 << 16);
        }
        // wlocA into sP (slots 0..15 = weights, 16..31 = 0)
#pragma unroll
        for (int i = 0; i < 4; ++i) {
            int m = 4 * i + y;
            int slot = 2 * (m & 7) + (m >> 3);
            sPu[bb * STR_P + slot] = f2bf(sw[m][bb]);
        }
        *(uint2*)&sPu[bb * STR_P + 16 + 4 * y] = make_uint2(0u, 0u);
    }
    __syncthreads();
    fx4 acc2[16];
#pragma unroll
    for (int dt = 0; dt < 16; ++dt) acc2[dt] = zero4;
    {
        bf16x8 pa2 = *(const bf16x8*)&sPu[(b0 + l) * STR_P + 8 * q];
#pragma unroll
        for (int dt = 0; dt < 16; ++dt) {
            bf16x8 eb2 = *(const bf16x8*)&sETu[0][offL + dt * 544 + q * 32];
            acc2[dt] = __builtin_amdgcn_mfma_f32_16x16x32_bf16(pa2, eb2, acc2[dt], 0, 0, 0);
        }
    }
    u16* nkp = numKp + (size_t)blockIdx.x * (B * D);
#pragma unroll
    for (int dt = 0; dt < 16; ++dt)
#pragma unroll
        for (int r = 0; r < 4; ++r)
            nkp[(b0 + 4 * q + r) * D + 16 * dt + l] = f2bf(acc2[dt][r]);
}

// ---- k_combine: global softmax rescale + 500-way partial reduce -> o_k, comb ----
__global__ __launch_bounds__(128) void k_combine(const u16* __restrict__ numCp,
                                                 const u16* __restrict__ numKp,
                                                 const float* __restrict__ mLp,
                                                 const float* __restrict__ denLp,
                                                 float* __restrict__ o_k,
                                                 float* __restrict__ comb) {
    __shared__ float sscale[512];
    __shared__ float red[128];
    int t = threadIdx.x;
    int b = blockIdx.x >> 1, h = blockIdx.x & 1;
    int d = h * 128 + t;
    // global max over 500 block-maxes
    float mx = -INFINITY;
#pragma unroll
    for (int k = 0; k < 4; ++k) {
        int blk = t + 128 * k;
        if (blk < NBLK) mx = fmaxf(mx, mLp[blk * B + b]);
    }
    red[t] = mx;
    __syncthreads();
    for (int s = 64; s > 0; s >>= 1) {
        if (t < s) red[t] = fmaxf(red[t], red[t + s]);
        __syncthreads();
    }
    float Mg = red[0];
    __syncthreads();
    float dsum = 0.f;
#pragma unroll
    for (int k = 0; k < 4; ++k) {
        int blk = t + 128 * k;
        if (blk < NBLK) {
            float sc = __expf(mLp[blk * B + b] - Mg);
            sscale[blk] = sc;
            dsum += sc * denLp[blk * B + b];
        }
    }
    red[t] = dsum;
    __syncthreads();
    for (int s = 64; s > 0; s >>= 1) {
        if (t < s) red[t] += red[t + s];
        __syncthreads();
    }
    float rden = 1.f / red[0];
    float ao = 0.f, ac = 0.f;
    for (int blk = 0; blk < NBLK; blk += 2) {
        float s0 = sscale[blk], s1 = sscale[blk + 1];
        size_t i0 = (size_t)blk * (B * D) + b * D + d;
        size_t i1 = i0 + (B * D);
        ao += s0 * bf2f(numKp[i0]) + s1 * bf2f(numKp[i1]);
        ac += s0 * bf2f(numCp[i0]) + s1 * bf2f(numCp[i1]);
    }
    o_k[b * D + d] = ao * rden;
    comb[b * D + d] = ac * rden;
}

// ==================== FALLBACK PATH (round-5, proven) ====================

__global__ __launch_bounds__(256) void fb_zero(float* __restrict__ o_k, float* __restrict__ comb,
                                               unsigned* __restrict__ rmax_u, float* __restrict__ ssum) {
    int t = threadIdx.x;
    float4 z = make_float4(0.f, 0.f, 0.f, 0.f);
    if (blockIdx.x < 16) ((float4*)o_k)[blockIdx.x * 256 + t] = z;
    else if (blockIdx.x < 32) ((float4*)comb)[(blockIdx.x - 16) * 256 + t] = z;
    else { if (t < 64) rmax_u[t] = 0u; else if (t < 128) ssum[t - 64] = 0.f; }
}

__global__ __launch_bounds__(256) void fb_conv(const float* __restrict__ emb, u16* __restrict__ embb,
                                               const float* __restrict__ query, u16* __restrict__ qbf) {
    int t = threadIdx.x;
    if (blockIdx.x < 6250) {
        size_t idx = (size_t)blockIdx.x * 2048 + (size_t)t * 8;
        float4 v0 = *(const float4*)(emb + idx);
        float4 v1 = *(const float4*)(emb + idx + 4);
        u16 h[8] = {f2bf(v0.x), f2bf(v0.y), f2bf(v0.z), f2bf(v0.w),
                    f2bf(v1.x), f2bf(v1.y), f2bf(v1.z), f2bf(v1.w)};
        *(uint4*)(embb + idx) = *(uint4*)h;
    } else {
        size_t idx = (size_t)(blockIdx.x - 6250) * 2048 + (size_t)t * 8;
        float4 v0 = *(const float4*)(query + idx);
        float4 v1 = *(const float4*)(query + idx + 4);
        u16 h[8] = {f2bf(v0.x), f2bf(v0.y), f2bf(v0.z), f2bf(v0.w),
                    f2bf(v1.x), f2bf(v1.y), f2bf(v1.z), f2bf(v1.w)};
        *(uint4*)(qbf + idx) = *(uint4*)h;
    }
}

__global__ __launch_bounds__(256) void fb_pre(const int* __restrict__ keys, const float* __restrict__ emb,
                                              const float* __restrict__ q, const float* __restrict__ W,
                                              const float* __restrict__ bias, u16* __restrict__ keb,
                                              u16* __restrict__ vqb) {
    __shared__ float qs[D];
    int t = threadIdx.x;
    if (blockIdx.x < 1000) {
        int c = blockIdx.x * 256 + t;
        int j = c >> 5, sp = c & 31;
        int id = keys[j];
        const float* rp = emb + (size_t)id * D + sp * 8;
        float4 v0 = *(const float4*)rp;
        float4 v1 = *(const float4*)(rp + 4);
        float msk = (id != 0) ? 1.f : 0.f;
        u16 h[8] = {f2bf(v0.x * msk), f2bf(v0.y * msk), f2bf(v0.z * msk), f2bf(v0.w * msk),
                    f2bf(v1.x * msk), f2bf(v1.y * msk), f2bf(v1.z * msk), f2bf(v1.w * msk)};
        *(uint4*)(keb + (size_t)j * D + sp * 8) = *(uint4*)h;
    } else {
        int b = blockIdx.x - 1000;
        qs[t] = q[b * D + t];
        __syncthreads();
        const float* wr = W + t * D;
        float acc = bias[t];
#pragma unroll 8
        for (int k = 0; k < D; k += 4) {
            float4 w4 = *(const float4*)(wr + k);
            acc += qs[k] * w4.x + qs[k + 1] * w4.y + qs[k + 2] * w4.z + qs[k + 3] * w4.w;
        }
        vqb[b * D + t] = f2bf(acc);
    }
}

__global__ __launch_bounds__(256) void fb_logits(const u16* __restrict__ qbf, const u16* __restrict__ keb,
                                                 float* __restrict__ lg, unsigned* __restrict__ rmax_u) {
    int t = threadIdx.x;
    int lane = t & 63, l = lane & 15, q = lane >> 4, w = t >> 6;
    int m0 = blockIdx.x * 16;
    int b0 = 16 * w;
    fx4 acc = {0.f, 0.f, 0.f, 0.f};
#pragma unroll
    for (int s = 0; s < 8; ++s) {
        bf16x8 a  = *(const bf16x8*)(qbf + (size_t)(b0 + l) * D + 32 * s + 8 * q);
        bf16x8 bb = *(const bf16x8*)(keb + (size_t)(m0 + l) * D + 32 * s + 8 * q);
        acc = __builtin_amdgcn_mfma_f32_16x16x32_bf16(a, bb, acc, 0, 0, 0);
    }
#pragma unroll
    for (int r = 0; r < 4; ++r) {
        lg[(size_t)(b0 + 4 * q + r) * LG_LD + m0 + l] = acc[r];
        float mx = acc[r];
        mx = fmaxf(mx, __shfl_xor(mx, 1));
        mx = fmaxf(mx, __shfl_xor(mx, 2));
        mx = fmaxf(mx, __shfl_xor(mx, 4));
        mx = fmaxf(mx, __shfl_xor(mx, 8));
        if (l == 0) atomicMax(&rmax_u[b0 + 4 * q + r], fmax_key(mx));
    }
}

__global__ __launch_bounds__(256) void fb_w(const float* __restrict__ lg, const unsigned* __restrict__ rmax_u,
                                            float* __restrict__ wT, float* __restrict__ ssum) {
    __shared__ float tile[64][65];
    __shared__ float psum[4][64];
    int t = threadIdx.x;
    int x = t & 63, y = t >> 6;
    int m0 = blockIdx.x * 64;
#pragma unroll
    for (int i = 0; i < 16; ++i) {
        int b = 4 * i + y;
        float rm = fmax_unkey(rmax_u[b]);
        tile[b][x] = __expf(lg[(size_t)b * LG_LD + m0 + x] - rm);
    }
    __syncthreads();
    float ps = 0.f;
#pragma unroll
    for (int i = 0; i < 16; ++i) {
        int m = 4 * i + y;
        float v = tile[x][m];
        wT[(m0 + m) * 64 + x] = v;
        ps += v;
    }
    psum[y][x] = ps;
    __syncthreads();
    if (t < 64)
        atomicAdd(&ssum[t], psum[0][t] + psum[1][t] + psum[2][t] + psum[3][t]);
}

__global__ __launch_bounds__(256) void fb_ok(const u16* __restrict__ keb, const float* __restrict__ wT,
                                             const float* __restrict__ ssum, float* __restrict__ o_k) {
    __shared__ float sinv[16];
    int t = threadIdx.x;
    int bg = blockIdx.x >> 5;
    int jc = blockIdx.x & 31;
    if (t < 16) sinv[t] = 1.f / ssum[bg * 16 + t];
    __syncthreads();
    int j0 = jc * 250;
    float acc[16] = {};
    for (int j = j0; j < j0 + 250; ++j) {
        float kv = bf2f(keb[(size_t)j * D + t]);
        const float4* w4 = (const float4*)(wT + j * 64 + bg * 16);
        float4 wa = w4[0], wb = w4[1], wc = w4[2], wd = w4[3];
        acc[0]  += wa.x * kv; acc[1]  += wa.y * kv; acc[2]  += wa.z * kv; acc[3]  += wa.w * kv;
        acc[4]  += wb.x * kv; acc[5]  += wb.y * kv; acc[6]  += wb.z * kv; acc[7]  += wb.w * kv;
        acc[8]  += wc.x * kv; acc[9]  += wc.y * kv; acc[10] += wc.z * kv; acc[11] += wc.w * kv;
        acc[12] += wd.x * kv; acc[13] += wd.y * kv; acc[14] += wd.z * kv; acc[15] += wd.w * kv;
    }
#pragma unroll
    for (int i = 0; i < 16; ++i)
        atomicAdd(&o_k[(bg * 16 + i) * D + t], acc[i] * sinv[i]);
}

__global__ __launch_bounds__(256, 3) void fb_heavy(const int* __restrict__ entries,
                                                   const u16* __restrict__ embb,
                                                   const u16* __restrict__ vqb,
                                                   const float* __restrict__ wTp,
                                                   const float* __restrict__ ssum,
                                                   float* __restrict__ comb) {
    __shared__ __align__(16) u16 sEu[N * STR_E];
    __shared__ __align__(16) u16 sETu[64 * 136];
    __shared__ __align__(16) u16 sPu[B * STR_P];
    __shared__ float swl[B];
    int t = threadIdx.x;
    int lane = t & 63, l = lane & 15, q = lane >> 4, w = t >> 6;
    int b0 = 16 * w;
    int sp = t & 31, n0 = t >> 5;
    float my_sinv = (t < B) ? 1.f / ssum[t] : 0.f;
    bf16x8 vqf[8];
#pragma unroll
    for (int s = 0; s < 8; ++s)
        vqf[s] = *(const bf16x8*)(vqb + (b0 + l) * D + 32 * s + 8 * q);
    fx4 zero4 = {0.f, 0.f, 0.f, 0.f};
    fx4 acc[16];
#pragma unroll
    for (int dt = 0; dt < 16; ++dt) acc[dt] = zero4;
    int m0 = blockIdx.x * 8;
    int idc[4], idn[4];
#pragma unroll
    for (int i = 0; i < 4; ++i) idc[i] = entries[m0 * N + n0 + 8 * i];
    uint4 pf[4];
#pragma unroll
    for (int i = 0; i < 4; ++i)
        pf[i] = *(const uint4*)(embb + (size_t)idc[i] * D + sp * 8);
#pragma unroll
    for (int i = 0; i < 4; ++i) idn[i] = entries[(m0 + 1) * N + n0 + 8 * i];
    int offL = (l >> 2) * 136 + (l & 3) * 8;
    for (int e = 0; e < 8; ++e) {
        __syncthreads();
#pragma unroll
        for (int i = 0; i < 4; ++i) {
            if (idc[i] == 0) pf[i] = make_uint4(0u, 0u, 0u, 0u);
            *(uint4*)&sEu[(n0 + 8 * i) * STR_E + sp * 8] = pf[i];
        }
#pragma unroll
        for (int j = 0; j < 8; ++j) {
            unsigned a0 = (((unsigned*)&pf[0])[j >> 1] >> ((j & 1) * 16)) & 0xFFFFu;
            unsigned a1 = (((unsigned*)&pf[1])[j >> 1] >> ((j & 1) * 16)) & 0xFFFFu;
            unsigned a2 = (((unsigned*)&pf[2])[j >> 1] >> ((j & 1) * 16)) & 0xFFFFu;
            unsigned a3 = (((unsigned*)&pf[3])[j >> 1] >> ((j & 1) * 16)) & 0xFFFFu;
            uint2 pr = make_uint2(a0 | (a1 << 16), a2 | (a3 << 16));
            int off = (2 * sp + (j >> 2)) * 136 + (n0 >> 1) * 32 + (j & 3) * 8 + (n0 & 1) * 4;
            *(uint2*)&sETu[off] = pr;
        }
        if (t < B) swl[t] = wTp[(m0 + e) * B + t] * my_sinv;
        if (e + 1 < 8) {
#pragma unroll
            for (int i = 0; i < 4; ++i)
                pf[i] = *(const uint4*)(embb + (size_t)idn[i] * D + sp * 8);
#pragma unroll
            for (int i = 0; i < 4; ++i) idc[i] = idn[i];
            if (e + 2 < 8) {
#pragma unroll
                for (int i = 0; i < 4; ++i) idn[i] = entries[(m0 + e + 2) * N + n0 + 8 * i];
            }
        }
        __syncthreads();
        fx4 accS[2];
        accS[0] = zero4; accS[1] = zero4;
#pragma unroll
        for (int T = 0; T < 2; ++T)
#pragma unroll
            for (int s = 0; s < 8; ++s) {
                bf16x8 ea = *(const bf16x8*)&sEu[(16 * T + l) * STR_E + 32 * s + 8 * q];
                accS[T] = __builtin_amdgcn_mfma_f32_16x16x32_bf16(ea, vqf[s], accS[T], 0, 0, 0);
            }
        float swb = swl[b0 + l];
        float mx = -INFINITY;
#pragma unroll
        for (int T = 0; T < 2; ++T)
#pragma unroll
            for (int r = 0; r < 4; ++r) mx = fmaxf(mx, accS[T][r]);
        mx = fmaxf(mx, __shfl_xor(mx, 16));
        mx = fmaxf(mx, __shfl_xor(mx, 32));
        float pe[2][4], sum = 0.f;
#pragma unroll
        for (int T = 0; T < 2; ++T)
#pragma unroll
            for (int r = 0; r < 4; ++r) {
                pe[T][r] = __expf(accS[T][r] - mx);
                sum += pe[T][r];
            }
        sum += __shfl_xor(sum, 16);
        sum += __shfl_xor(sum, 32);
        float sc = swb / sum;
#pragma unroll
        for (int T = 0; T < 2; ++T)
#pragma unroll
            for (int r = 0; r < 4; ++r) {
                int nn = 16 * T + 4 * q + r;
                int slot = 4 * (nn & 7) + (nn >> 3);
                sPu[(b0 + l) * STR_P + slot] = f2bf(pe[T][r] * sc);
            }
        bf16x8 pa = *(const bf16x8*)&sPu[(b0 + l) * STR_P + 8 * q];
#pragma unroll
        for (int dt = 0; dt < 16; ++dt) {
            bf16x8 eb = *(const bf16x8*)&sETu[offL + dt * 544 + q * 32];
            acc[dt] = __builtin_amdgcn_mfma_f32_16x16x32_bf16(pa, eb, acc[dt], 0, 0, 0);
        }
    }
#pragma unroll
    for (int dt = 0; dt < 16; ++dt)
#pragma unroll
        for (int r = 0; r < 4; ++r)
            atomicAdd(&comb[(b0 + 4 * q + r) * D + 16 * dt + l], acc[dt][r]);
}

// ==================== launcher ====================

extern "C" void kernel_launch(void* const* d_in, const int* in_sizes, int n_in,
                              void* d_out, int out_size, void* d_ws, size_t ws_size,
                              hipStream_t stream) {
    const int*   keys    = (const int*)d_in[0];
    const int*   entries = (const int*)d_in[1];
    const float* query   = (const float*)d_in[2];
    const float* wordemb = (const float*)d_in[3];
    const float* qproj_w = (const float*)d_in[4];
    const float* qproj_b = (const float*)d_in[5];

    float* out  = (float*)d_out;
    float* o_k  = out;
    float* lg   = out + B * D;
    float* comb = out + B * D + B * M;

    char* wsb = (char*)d_ws;
    const size_t FLASH_WS = 64833536;

    if (ws_size >= FLASH_WS) {
        u16*   embb  = (u16*)wsb;                       // 25,600,000 B
        u16*   keb   = (u16*)(wsb + 25600000);          //  4,096,000 B
        u16*   qbf   = (u16*)(wsb + 29696000);          //     32,768 B
        u16*   vqb   = (u16*)(wsb + 29728768);          //     32,768 B
        float* lgT   = (float*)(wsb + 29761536);        //  2,048,000 B
        u16*   numCp = (u16*)(wsb + 31809536);          // 16,384,000 B
        u16*   numKp = (u16*)(wsb + 48193536);          // 16,384,000 B
        float* mLp   = (float*)(wsb + 64577536);        //    128,000 B
        float* denLp = (float*)(wsb + 64705536);        //    128,000 B

        k_prep<<<7322, 256, 0, stream>>>(keys, wordemb, query, qproj_w, qproj_b,
                                         embb, qbf, keb, vqb);
        k_logits_f<<<NBLK, 256, 0, stream>>>(qbf, keb, lg, lgT);
        k_heavy_f<<<NBLK, 256, 0, stream>>>(entries, embb, vqb, keb, lgT,
                                            numCp, numKp, mLp, denLp);
        k_combine<<<128, 128, 0, stream>>>(numCp, numKp, mLp, denLp, o_k, comb);
    } else {
        u16*      embb   = (u16*)wsb;
        u16*      keb    = (u16*)(wsb + 25600000);
        u16*      qbf    = (u16*)(wsb + 29696000);
        u16*      vqb    = (u16*)(wsb + 29728768);
        float*    wT     = (float*)(wsb + 29761536);
        unsigned* rmax_u = (unsigned*)(wsb + 31809536);
        float*    ssum   = (float*)(wsb + 31809792);

        fb_zero<<<33, 256, 0, stream>>>(o_k, comb, rmax_u, ssum);
        fb_conv<<<6258, 256, 0, stream>>>(wordemb, embb, query, qbf);
        fb_pre<<<1064, 256, 0, stream>>>(keys, wordemb, query, qproj_w, qproj_b, keb, vqb);
        fb_logits<<<M / 16, 256, 0, stream>>>(qbf, keb, lg, rmax_u);
        fb_w<<<M / 64, 256, 0, stream>>>(lg, rmax_u, wT, ssum);
        fb_ok<<<128, 256, 0, stream>>>(keb, wT, ssum, o_k);
        fb_heavy<<<M / 8, 256, 0, stream>>>(entries, embb, vqb, wT, ssum, comb);
    }
}